// Round 3
// baseline (227.024 us; speedup 1.0000x reference)
//
#include <hip/hip_runtime.h>
#include <hip/hip_bf16.h>

// Conv2d: in (32,128,56,56) f32, w (256,128,3,3) f32, bias(256) f32
// out (32,256,56,56) f32.  Implicit-GEMM, bf16 MFMA.
//
// R3: conv rewritten to the 256x256 8-phase pipelined template (T2+T3+T4+T5):
//   - tile 256M (8h x 32w, w-tiles {0,24} overlap) x 256N (all ko), BK=64
//   - 512 thr = 8 waves (2 mw x 4 nw), per-wave 128x64 via mfma_f32_32x32x16
//   - LDS 128 KB: 2 slots x (A 32KB + B 32KB), dynamic shared mem
//   - per K-tile 4 phases (quadrants); staging stream = 1 half-unit/phase
//     (2 global_load_lds per wave) into the region freed one phase earlier:
//     Aq0@P2, Br0@P3, Br1@P4, Aq1@P5 (tile t+2); Aq0@P6, Br0@P7, Br1@P8,
//     Aq1@P1' (tile t+3).  vmcnt(6) before the closing barrier of P4/P8
//     (per-wave wait + barrier => global arrival guarantee); last iter
//     drains vmcnt(0) at P4.
//   - chunk swizzle cc ^= (row&7) baked into the per-lane GLOBAL source
//     (gl_lds dest stays lane-linear), same scheme as R2, bank-conflict-free.
// prep_fused / fallback unchanged from R2 (verified).
//
// ws:  [0, 1MB)           : w2  bf16 [9][256][128]
//      [1MB, 1MB+30.4MB)  : in_pad bf16 [32][58][64][128] (zero-padded NHWC)

typedef __bf16 bf16x8 __attribute__((ext_vector_type(8)));
typedef float f32x4 __attribute__((ext_vector_type(4)));
typedef float f32x16 __attribute__((ext_vector_type(16)));

#define N_IMG 32
#define C_IN 128
#define HW 56
#define K_OUT 256
#define YPAD 58
#define XPAD 64
#define IN_PAD_OFF 1048576ul
#define NWGB 144                       // weight-prep blocks in fused prep

__device__ __forceinline__ void gl_lds16(const __bf16* g, __bf16* l) {
    __builtin_amdgcn_global_load_lds(
        (const __attribute__((address_space(1))) unsigned int*)(const void*)g,
        (__attribute__((address_space(3))) unsigned int*)(void*)l,
        16, 0, 0);
}

// ---- fused pre-pass: blocks [0,144) weight OIHW f32 -> [rs][ko][c] bf16;
//      blocks [144, 144+1856) input NCHW f32 -> padded NHWC bf16. (as R2)
__global__ void prep_fused(const float* __restrict__ wt, __bf16* __restrict__ w2,
                           const float* __restrict__ in, __bf16* __restrict__ in_pad) {
    __shared__ float tile[HW * 130];      // used by input path only
    if (blockIdx.x < NWGB) {
        int idx = blockIdx.x * 256 + threadIdx.x;   // 9*256*16 = 36864 items
        if (idx >= 9 * K_OUT * 16) return;
        int c8 = idx & 15;
        int ko = (idx >> 4) & 255;
        int rs = idx >> 12;
        const float* src = wt + ((size_t)ko * C_IN + c8 * 8) * 9 + rs;
        bf16x8 v8;
#pragma unroll
        for (int k = 0; k < 8; ++k) v8[k] = (__bf16)src[k * 9];
        *(bf16x8*)(w2 + (size_t)idx * 8) = v8;      // = [rs][ko][c8*8..+8]
        return;
    }
    int bid = blockIdx.x - NWGB;          // 32*58 = 1856
    int y = bid % YPAD;
    int n = bid / YPAD;
    int h = y - 1;
    bool interior = (h >= 0 && h < HW);
    int t = threadIdx.x;
    if (interior) {
        const float* src = in + (size_t)n * C_IN * (HW * HW) + (size_t)h * HW;
#pragma unroll 1
        for (int idx = t; idx < C_IN * 14; idx += 256) {   // float4 reads
            int c = idx / 14, g = idx % 14;
            f32x4 v = *(const f32x4*)(src + (size_t)c * (HW * HW) + g * 4);
            int w = g * 4;
            tile[(w + 0) * 130 + c] = v.x;
            tile[(w + 1) * 130 + c] = v.y;
            tile[(w + 2) * 130 + c] = v.z;
            tile[(w + 3) * 130 + c] = v.w;
        }
    }
    __syncthreads();
    __bf16* dst = in_pad + (size_t)(n * YPAD + y) * XPAD * C_IN;
#pragma unroll 1
    for (int idx = t; idx < XPAD * 16; idx += 256) {       // 16B stores
        int x = idx >> 4, cg = idx & 15;
        bf16x8 v8;
        if (interior && x >= 1 && x <= HW) {
            const float* tp = tile + (x - 1) * 130 + cg * 8;
#pragma unroll
            for (int k = 0; k < 8; ++k) v8[k] = (__bf16)tp[k];
        } else {
#pragma unroll
            for (int k = 0; k < 8; ++k) v8[k] = (__bf16)0.f;
        }
        *(bf16x8*)(dst + x * C_IN + cg * 8) = v8;
    }
}

// ---------------- main kernel: 8-phase pipelined implicit-GEMM conv -----------
#define BAR()   do { asm volatile("" ::: "memory"); __builtin_amdgcn_s_barrier(); \
                     asm volatile("" ::: "memory"); } while (0)
#define LGKM0() do { asm volatile("s_waitcnt lgkmcnt(0)" ::: "memory"); \
                     __builtin_amdgcn_sched_barrier(0); } while (0)

#define LOAD_A(Q, SLOT) do {                                                   \
    const __bf16* _pa = lds_ + (SLOT) * 16384 + (mw * 128 + (Q) * 64 + l31) * 64; \
    _Pragma("unroll") for (int ks = 0; ks < 4; ++ks)                           \
    _Pragma("unroll") for (int m = 0; m < 2; ++m)                              \
        aR[ks][m] = *(const bf16x8*)(_pa + m * 2048 + ((ks * 2 + hi) ^ l7) * 8); \
} while (0)

#define LOAD_B(R, SLOT, BARR) do {                                             \
    const __bf16* _pb = lds_ + 32768 + (SLOT) * 16384 + (nw * 64 + (R) * 32 + l31) * 64; \
    _Pragma("unroll") for (int ks = 0; ks < 4; ++ks)                           \
        BARR[ks] = *(const bf16x8*)(_pb + ((ks * 2 + hi) ^ l7) * 8);           \
} while (0)

#define MM(Q, R, BARR) do {                                                    \
    __builtin_amdgcn_s_setprio(1);                                             \
    _Pragma("unroll") for (int ks = 0; ks < 4; ++ks) {                         \
        acc[(Q) * 2 + 0][(R)] = __builtin_amdgcn_mfma_f32_32x32x16_bf16(       \
            aR[ks][0], BARR[ks], acc[(Q) * 2 + 0][(R)], 0, 0, 0);              \
        acc[(Q) * 2 + 1][(R)] = __builtin_amdgcn_mfma_f32_32x32x16_bf16(       \
            aR[ks][1], BARR[ks], acc[(Q) * 2 + 1][(R)], 0, 0, 0);              \
    }                                                                          \
    __builtin_amdgcn_s_setprio(0);                                             \
    __builtin_amdgcn_sched_barrier(0);                                         \
} while (0)

#define STAGE_A(TT, Q, SLOT) do {                                              \
    int _rs = (TT) >> 1;                                                       \
    int _r = (_rs * 11) >> 5;                                                  \
    int _s = _rs - 3 * _r;                                                     \
    const __bf16* _src = aG + (_r * XPAD + _s) * C_IN + (((TT) & 1) << 6);     \
    __bf16* _d = lds_ + (SLOT) * 16384 + (Q) * 4096 + wave * 512;              \
    gl_lds16(_src + aoffA[(Q)][0], _d);                                        \
    gl_lds16(_src + aoffA[(Q)][1], _d + 8192);                                 \
} while (0)

#define STAGE_B(TT, R, SLOT) do {                                              \
    int _rs = (TT) >> 1;                                                       \
    const __bf16* _src = w2 + _rs * (K_OUT * C_IN) + (((TT) & 1) << 6);        \
    gl_lds16(_src + boffB[(R)][0], lds_ + 32768 + (SLOT) * 16384 + bDst[(R)][0]); \
    gl_lds16(_src + boffB[(R)][1], lds_ + 32768 + (SLOT) * 16384 + bDst[(R)][1]); \
} while (0)

__global__ __launch_bounds__(512) void conv_mfma(
        const __bf16* __restrict__ in_pad,   // [32][58][64][128]
        const __bf16* __restrict__ w2,       // [9][256][128]
        const float* __restrict__ bias,
        float* __restrict__ out)             // [32][256][56][56]
{
    extern __shared__ __bf16 lds_[];         // 128 KB: A[2][16384], B[2][16384]

    // XCD-chunked bijective remap (448 = 8 XCDs x 56 blocks).
    int bid = (blockIdx.x & 7) * 56 + (blockIdx.x >> 3);
    int wt_ = bid & 1;
    int ht  = (bid >> 1) % 7;
    int n   = bid / 14;

    int h0 = ht * 8;
    int w0 = wt_ * 24;                       // {0, 24}; w 24..31 overlap (benign)

    int tid  = threadIdx.x;
    int lane = tid & 63;
    int wave = tid >> 6;                     // 0..7
    int mw   = wave & 1;                     // M-split (2)
    int nw   = wave >> 1;                    // N-split (4)
    int l31  = lane & 31;
    int l7   = lane & 7;
    int hi   = lane >> 5;                    // k-half within 32x32 frag

    // staging source offsets (swizzle baked into global addr) + B LDS dests
    int aoffA[2][2], boffB[2][2], bDst[2][2];
#pragma unroll
    for (int q = 0; q < 2; ++q)
#pragma unroll
        for (int j = 0; j < 2; ++j) {
            int id  = j * 512 + tid;         // chunk id within 16KB unit
            int riu = id >> 3, cs = id & 7;
            int row = q * 64 + (riu & 63) + (riu >> 6) * 128;      // A M-row
            aoffA[q][j] = ((row >> 5) * XPAD + (row & 31)) * C_IN
                        + (cs ^ (row & 7)) * 8;
            int ko = q * 32 + (riu & 31) + (riu >> 5) * 64;        // B ko-row
            boffB[q][j] = ko * C_IN + (cs ^ (ko & 7)) * 8;
            bDst[q][j]  = (q * 32 + (wave & 3) * 8 + (j * 2 + (wave >> 2)) * 64) * 64;
        }

    const __bf16* aG = in_pad + (((size_t)n * YPAD + h0) * XPAD + w0) * C_IN;

    bf16x8 aR[4][2];
    bf16x8 bR0[4], bR1[4];
    f32x16 acc[4][2] = {};

    // ---- prologue: tile0 (4 units) + tile1 (3 units); wait tile0; barrier ----
    STAGE_A(0, 0, 0); STAGE_B(0, 0, 0); STAGE_B(0, 1, 0); STAGE_A(0, 1, 0);
    STAGE_A(1, 0, 1); STAGE_B(1, 0, 1); STAGE_B(1, 1, 1);
    asm volatile("s_waitcnt vmcnt(6)" ::: "memory");
    BAR();

#pragma unroll 1
    for (int I = 0; I < 9; ++I) {            // tiles t0=2I (slot0), t1=2I+1 (slot1)
        int t1 = 2 * I + 1, t2 = 2 * I + 2, t3 = 2 * I + 3;
        bool more = (I < 8);
        // P1: read a_q0,b_r0(t0); stage Aq1(t1)
        LOAD_A(0, 0); LOAD_B(0, 0, bR0);
        STAGE_A(t1, 1, 1);
        BAR(); LGKM0(); MM(0, 0, bR0); BAR();
        // P2: read b_r1(t0); stage Aq0(t2)
        LOAD_B(1, 0, bR1);
        if (more) STAGE_A(t2, 0, 0);
        BAR(); LGKM0(); MM(0, 1, bR1); BAR();
        // P3: read a_q1(t0); stage Br0(t2)
        LOAD_A(1, 0);
        if (more) STAGE_B(t2, 0, 0);
        BAR(); LGKM0(); MM(1, 1, bR1); BAR();
        // P4: stage Br1(t2); MFMA; counted vmcnt; barrier publishes arrivals
        if (more) STAGE_B(t2, 1, 0);
        BAR(); MM(1, 0, bR0);
        if (more) asm volatile("s_waitcnt vmcnt(6)" ::: "memory");
        else      asm volatile("s_waitcnt vmcnt(0)" ::: "memory");
        BAR();
        // P5: read a_q0,b_r0(t1); stage Aq1(t2)
        LOAD_A(0, 1); LOAD_B(0, 1, bR0);
        if (more) STAGE_A(t2, 1, 0);
        BAR(); LGKM0(); MM(0, 0, bR0); BAR();
        // P6: read b_r1(t1); stage Aq0(t3)
        LOAD_B(1, 1, bR1);
        if (more) STAGE_A(t3, 0, 1);
        BAR(); LGKM0(); MM(0, 1, bR1); BAR();
        // P7: read a_q1(t1); stage Br0(t3)
        LOAD_A(1, 1);
        if (more) STAGE_B(t3, 0, 1);
        BAR(); LGKM0(); MM(1, 1, bR1); BAR();
        // P8: stage Br1(t3); MFMA; counted vmcnt
        if (more) STAGE_B(t3, 1, 1);
        BAR(); MM(1, 0, bR0);
        if (more) asm volatile("s_waitcnt vmcnt(6)" ::: "memory");
        BAR();
    }

    // ---- epilogue: 32x32 D layout: col(ko)=l31, row(M)= (r&3)+8*(r>>2)+4*hi ----
#pragma unroll
    for (int mf = 0; mf < 4; ++mf) {
        int h = h0 + mw * 4 + mf;
#pragma unroll
        for (int rr = 0; rr < 2; ++rr) {
            int ko = nw * 64 + rr * 32 + l31;
            float bs = bias[ko];
            float* ob = out + (size_t)(n * K_OUT + ko) * (HW * HW)
                            + (size_t)h * HW + w0 + hi * 4;
            f32x16 v = acc[mf][rr];
#pragma unroll
            for (int q16 = 0; q16 < 4; ++q16) {
                f32x4 vv = { v[4 * q16 + 0] + bs, v[4 * q16 + 1] + bs,
                             v[4 * q16 + 2] + bs, v[4 * q16 + 3] + bs };
                *(f32x4*)(ob + q16 * 8) = vv;   // w = w0 + q16*8 + hi*4 + 0..3
            }
        }
    }
}

// ---------------- fallback: naive direct conv (only if ws too small) -----------
__global__ void conv_naive(const float* __restrict__ in, const float* __restrict__ wt,
                           const float* __restrict__ bias, float* __restrict__ out) {
    size_t idx = (size_t)blockIdx.x * 256 + threadIdx.x;
    size_t total = (size_t)N_IMG * K_OUT * HW * HW;
    if (idx >= total) return;
    int w  = idx % HW;
    int h  = (idx / HW) % HW;
    int ko = (idx / (HW * HW)) % K_OUT;
    int n  = idx / ((size_t)HW * HW * K_OUT);
    float acc = bias[ko];
    for (int c = 0; c < C_IN; ++c)
        for (int r = 0; r < 3; ++r) {
            int y = h + r - 1;
            if (y < 0 || y >= HW) continue;
            for (int s = 0; s < 3; ++s) {
                int x = w + s - 1;
                if (x < 0 || x >= HW) continue;
                acc += in[((size_t)(n * C_IN + c) * HW + y) * HW + x]
                     * wt[((size_t)ko * C_IN + c) * 9 + r * 3 + s];
            }
        }
    out[idx] = acc;
}

extern "C" void kernel_launch(void* const* d_in, const int* in_sizes, int n_in,
                              void* d_out, int out_size, void* d_ws, size_t ws_size,
                              hipStream_t stream) {
    const float* in   = (const float*)d_in[0];
    const float* wt   = (const float*)d_in[1];
    const float* bias = (const float*)d_in[2];
    float* out = (float*)d_out;

    size_t need = IN_PAD_OFF + (size_t)N_IMG * YPAD * XPAD * C_IN * 2;
    if (ws_size >= need) {
        static bool attr_set = false;
        if (!attr_set) {
            (void)hipFuncSetAttribute((const void*)conv_mfma,
                                      hipFuncAttributeMaxDynamicSharedMemorySize,
                                      131072);
            attr_set = true;
        }
        __bf16* w2     = (__bf16*)d_ws;
        __bf16* in_pad = (__bf16*)((char*)d_ws + IN_PAD_OFF);
        prep_fused<<<NWGB + N_IMG * YPAD, 256, 0, stream>>>(wt, w2, in, in_pad);
        conv_mfma<<<N_IMG * 7 * 2, 512, 131072, stream>>>(in_pad, w2, bias, out);
    } else {
        size_t total = (size_t)N_IMG * K_OUT * HW * HW;
        conv_naive<<<(unsigned)((total + 255) / 256), 256, 0, stream>>>(in, wt, bias, out);
    }
}